// Round 11
// baseline (177.353 us; speedup 1.0000x reference)
//
#include <hip/hip_runtime.h>

#define N 8192
#define T 512
#define S 4

typedef float fx4 __attribute__((ext_vector_type(4)));

__device__ __forceinline__ float dot4(float4 a, float4 b) {
    return a.x*b.x + a.y*b.y + a.z*b.z + a.w*b.w;
}
__device__ __forceinline__ void nt_store4(float4* p, float4 v) {
    fx4 r; r.x = v.x; r.y = v.y; r.z = v.z; r.w = v.w;
    __builtin_nontemporal_store(r, (fx4*)p);
}
__device__ __forceinline__ float4 nt_load4(const float4* p) {
    fx4 r = __builtin_nontemporal_load((const fx4*)p);
    float4 o; o.x = r.x; o.y = r.y; o.z = r.z; o.w = r.w; return o;
}

// ---------------- K1: thread-per-t bias, pure sequential streaming ----------
// b[n*T+t] = proj(n,t) + aY*Y[n,t-1] (t>=1);  b[n*T+0] = mu_init + proj.
// Block owns 2048 contiguous ids. All inputs read-once -> NT loads (keep L3
// for b). b store stays cached (re-read 4x by k_scan).
__global__ __launch_bounds__(256) void k_bias(
        const float* __restrict__ drivers,
        const float* __restrict__ cov,
        const float* __restrict__ Y,
        const float* __restrict__ gamma_w,
        const float* __restrict__ alpha_w,
        const float* __restrict__ alpha_Y_lag,
        const float* __restrict__ mu_init,
        float* __restrict__ b) {
    const float4* g4 = (const float4*)gamma_w;
    const float4* a4 = (const float4*)alpha_w;
    const float4 g0 = g4[0], g1 = g4[1];
    const float4 w0 = a4[0], w1 = a4[1], w2 = a4[2], w3 = a4[3];
    const float aY   = alpha_Y_lag[0];
    const float mu0c = mu_init[0];

    const size_t base = (size_t)blockIdx.x * 2048 + threadIdx.x;
    const float4* d4 = (const float4*)drivers;
    const float4* c4 = (const float4*)cov;

    #pragma unroll 4
    for (int it = 0; it < 8; ++it) {
        const size_t id = base + (size_t)it * 256;       // id = n*T + t
        float4 dA = nt_load4(&d4[id * 2]),     dB = nt_load4(&d4[id * 2 + 1]);
        float4 cA = nt_load4(&c4[id * 4]),     cB = nt_load4(&c4[id * 4 + 1]);
        float4 cC = nt_load4(&c4[id * 4 + 2]), cD = nt_load4(&c4[id * 4 + 3]);
        const float yprev = __builtin_nontemporal_load(&Y[id > 0 ? id - 1 : 0]);
        const float proj = dot4(dA, g0) + dot4(dB, g1)
                         + dot4(cA, w0) + dot4(cB, w1)
                         + dot4(cC, w2) + dot4(cD, w3);
        const int t = (int)(id & (T - 1));
        b[id] = (t == 0) ? (mu0c + proj) : (proj + aY * yprev);
    }
}

// ---------------- K2: sample-major wave scan, no LDS, no barriers ----------
// blockIdx = s*(N/4) + g ; wave wv handles chain (s, n = 4g+wv).
// Block streams: eps (NT, read-once), b (cached, L3-resident), Z/mu/lv (NT).
__global__ __launch_bounds__(256) void k_scan(
        const float* __restrict__ bg,
        const float* __restrict__ eps,
        const float* __restrict__ tilde_psi,
        const float* __restrict__ log_tilde_sigma,
        const float* __restrict__ log_sigma_init,
        float* __restrict__ Zout,
        float* __restrict__ muout,
        float* __restrict__ lvout) {
    const int lane = threadIdx.x & 63;
    const int wv   = threadIdx.x >> 6;
    const int s    = blockIdx.x >> 11;            // / (N/4) = 2048
    const int g    = blockIdx.x & 2047;
    const int n    = g * 4 + wv;

    const float psi    = tilde_psi[0];
    const float lts    = log_tilde_sigma[0];
    const float lsi    = log_sigma_init[0];
    const float sigma  = expf(lts);
    const float sigma0 = expf(lsi);
    const float lvv    = 2.f * lts;

    // all global loads upfront
    const size_t chain = ((size_t)s * N + n) * (T / 4);   // float4 units
    const float4* e4 = (const float4*)eps + chain;
    const float4* b4 = (const float4*)bg + (size_t)n * (T / 4);
    const float4 eA = nt_load4(&e4[lane]), eB = nt_load4(&e4[64 + lane]);
    const float4 bA = b4[lane],            bB = b4[64 + lane];

    const float pj1 = psi, pj2 = psi * psi, pj3 = pj2 * psi, pj4 = pj2 * pj2;
    const float wd0 = pj4, wd1 = wd0 * wd0, wd2 = wd1 * wd1,
                wd3 = wd2 * wd2, wd4 = wd3 * wd3, wd5 = wd4 * wd4;
    // p4l = psi^(4*lane)
    float p4l = 1.f;
    {
        float pw = pj4;
        p4l *= (lane & 1)  ? pw : 1.f; pw *= pw;
        p4l *= (lane & 2)  ? pw : 1.f; pw *= pw;
        p4l *= (lane & 4)  ? pw : 1.f; pw *= pw;
        p4l *= (lane & 8)  ? pw : 1.f; pw *= pw;
        p4l *= (lane & 16) ? pw : 1.f; pw *= pw;
        p4l *= (lane & 32) ? pw : 1.f;
    }

    float4* z4 = (float4*)Zout  + chain;
    float4* m4 = (float4*)muout + chain;
    float4* l4 = (float4*)lvout + chain;

    float Zlast = 0.f;
    #pragma unroll
    for (int seg = 0; seg < 2; ++seg) {
        const float4 e  = seg ? eB : eA;
        const float4 bq = seg ? bB : bA;

        const float sg0 = (seg == 0 && lane == 0) ? sigma0 : sigma;
        // local inclusive scan from zero state
        const float z0 = bq.x + sg0 * e.x;
        const float z1 = psi * z0 + (bq.y + sigma * e.y);
        const float z2 = psi * z1 + (bq.z + sigma * e.z);
        const float z3 = psi * z2 + (bq.w + sigma * e.w);

        // wave-level weighted inclusive scan of carries (psi^4 per step)
        float v = z3, up;
        up = __shfl_up(v, 1);  v += (lane >= 1)  ? wd0 * up : 0.f;
        up = __shfl_up(v, 2);  v += (lane >= 2)  ? wd1 * up : 0.f;
        up = __shfl_up(v, 4);  v += (lane >= 4)  ? wd2 * up : 0.f;
        up = __shfl_up(v, 8);  v += (lane >= 8)  ? wd3 * up : 0.f;
        up = __shfl_up(v, 16); v += (lane >= 16) ? wd4 * up : 0.f;
        up = __shfl_up(v, 32); v += (lane >= 32) ? wd5 * up : 0.f;

        float Zprev = __shfl_up(v, 1);
        Zprev = (lane == 0) ? 0.f : Zprev;
        Zprev += p4l * Zlast;                  // bridge from segment A

        const float Z0 = z0 + pj1 * Zprev;
        const float Z1 = z1 + pj2 * Zprev;
        const float Z2 = z2 + pj3 * Zprev;
        const float Z3 = z3 + pj4 * Zprev;

        nt_store4(&z4[seg * 64 + lane], make_float4(Z0, Z1, Z2, Z3));
        nt_store4(&m4[seg * 64 + lane],
                  make_float4(Z0 - sg0 * e.x, Z1 - sigma * e.y,
                              Z2 - sigma * e.z, Z3 - sigma * e.w));
        nt_store4(&l4[seg * 64 + lane],
                  (seg == 0 && lane == 0)
                      ? make_float4(2.f * lsi, lvv, lvv, lvv)
                      : make_float4(lvv, lvv, lvv, lvv));

        Zlast = __shfl(Z3, 63);                // Z_255 broadcast
    }
}

// fallback lv fill (only if ws too small; then b lives in lvout)
__global__ __launch_bounds__(256) void k_lv(
        float* __restrict__ lv,
        const float* __restrict__ lts,
        const float* __restrict__ lsi) {
    int i = blockIdx.x * blockDim.x + threadIdx.x;    // float4 index
    float v = 2.0f * lts[0];
    float4 o = make_float4(v, v, v, v);
    if ((i & (T / 4 - 1)) == 0) o.x = 2.0f * lsi[0];
    ((float4*)lv)[i] = o;
}

extern "C" void kernel_launch(void* const* d_in, const int* in_sizes, int n_in,
                              void* d_out, int out_size, void* d_ws, size_t ws_size,
                              hipStream_t stream) {
    const float* drivers   = (const float*)d_in[0];
    const float* cov       = (const float*)d_in[1];
    const float* Y         = (const float*)d_in[2];
    const float* eps       = (const float*)d_in[3];
    const float* tilde_psi = (const float*)d_in[4];
    const float* gamma_w   = (const float*)d_in[5];
    const float* alpha_w   = (const float*)d_in[6];
    const float* aY        = (const float*)d_in[7];
    const float* lts       = (const float*)d_in[8];
    const float* mu_init   = (const float*)d_in[9];
    const float* lsi       = (const float*)d_in[10];

    float* out   = (float*)d_out;
    const size_t SNT = (size_t)S * N * T;
    float* Zout  = out;
    float* muout = out + SNT;
    float* lvout = out + 2 * SNT;

    const size_t bbytes = (size_t)N * T * sizeof(float);
    const bool ws_ok = (ws_size >= bbytes);
    float* b = ws_ok ? (float*)d_ws : lvout;      // observed ws_size ~1 GiB

    k_bias<<<(N * T) / 2048, 256, 0, stream>>>(drivers, cov, Y, gamma_w,
                                               alpha_w, aY, mu_init, b);
    k_scan<<<S * (N / 4), 256, 0, stream>>>(b, eps, tilde_psi, lts, lsi,
                                            Zout, muout, lvout);
    if (!ws_ok) {
        k_lv<<<(SNT / 4) / 256, 256, 0, stream>>>(lvout, lts, lsi);
    }
}

// Round 12
// 145.418 us; speedup vs baseline: 1.2196x; 1.2196x over previous
//
#include <hip/hip_runtime.h>

#define N 8192
#define T 512
#define S 4

typedef float fx4 __attribute__((ext_vector_type(4)));

__device__ __forceinline__ float dot4(float4 a, float4 b) {
    return a.x*b.x + a.y*b.y + a.z*b.z + a.w*b.w;
}
__device__ __forceinline__ void nt_store4(float4* p, float4 v) {
    fx4 r; r.x = v.x; r.y = v.y; r.z = v.z; r.w = v.w;
    __builtin_nontemporal_store(r, (fx4*)p);
}

// ---------------- K1: wave-streaming bias ----------------
// One wave per n-row. cov/drivers read as PURE SEQUENTIAL float4 streams
// (1 KiB per wave-instruction, full lines). Chunk dots reduced across
// adjacent lanes via shfl_xor; partials parked in wave-private LDS (no
// barriers needed); b written as coalesced 256 B scalar stores.
__global__ __launch_bounds__(256) void k_bias(
        const float* __restrict__ drivers,
        const float* __restrict__ cov,
        const float* __restrict__ Y,
        const float* __restrict__ gamma_w,
        const float* __restrict__ alpha_w,
        const float* __restrict__ alpha_Y_lag,
        const float* __restrict__ mu_init,
        float* __restrict__ b) {
    __shared__ float pc[4][T];        // proj_cov  per wave (8 KB)
    __shared__ float pd[4][T];        // proj_drv  per wave (8 KB)

    const int lane = threadIdx.x & 63;
    const int wid  = threadIdx.x >> 6;
    const int n    = blockIdx.x * 4 + wid;

    const float4* g4 = (const float4*)gamma_w;
    const float4* a4 = (const float4*)alpha_w;
    const float4 g0 = g4[0], g1 = g4[1];
    const float4 w0 = a4[0], w1 = a4[1], w2 = a4[2], w3 = a4[3];
    const float aY   = alpha_Y_lag[0];
    const float mu0c = mu_init[0];

    // per-lane fixed weight chunk (chunk index == lane&3 / lane&1)
    const float4 myw = (lane & 1) ? ((lane & 2) ? w3 : w1)
                                  : ((lane & 2) ? w2 : w0);
    const float4 myg = (lane & 1) ? g1 : g0;

    // ---- cov row: 2048 float4, 32 sequential 1 KiB instructions ----
    const float4* c4 = (const float4*)cov + (size_t)n * 2048;
    #pragma unroll 8
    for (int k = 0; k < 32; ++k) {
        const float4 c = c4[k * 64 + lane];     // flat f = k*64+lane
        float p = dot4(c, myw);                 // chunk = f&3 = lane&3
        p += __shfl_xor(p, 1);
        p += __shfl_xor(p, 2);                  // quad-reduced: t = f>>2
        if ((lane & 3) == 0) pc[wid][k * 16 + (lane >> 2)] = p;
    }

    // ---- drivers row: 1024 float4, 16 sequential 1 KiB instructions ----
    const float4* d4 = (const float4*)drivers + (size_t)n * 1024;
    #pragma unroll 8
    for (int k = 0; k < 16; ++k) {
        const float4 d = d4[k * 64 + lane];     // flat f = k*64+lane
        float p = dot4(d, myg);                 // chunk = f&1 = lane&1
        p += __shfl_xor(p, 1);                  // pair-reduced: t = f>>1
        if ((lane & 1) == 0) pd[wid][k * 32 + (lane >> 1)] = p;
    }

    // ---- combine + write b (wave-private LDS: no barrier needed) ----
    const float* Yrow = Y + (size_t)n * T;
    float* brow = b + (size_t)n * T;
    #pragma unroll
    for (int j = 0; j < 8; ++j) {
        const int t = j * 64 + lane;
        const float yprev = (t > 0) ? Yrow[t - 1] : 0.f;
        const float proj = pc[wid][t] + pd[wid][t];
        brow[t] = (t == 0) ? (mu0c + proj) : (proj + aY * yprev);
    }
}

// ---------------- K2: sample-major wave scan, no LDS, no barriers ----------
// blockIdx = s*(N/4) + g ; wave wv handles chain (s, n = 4g+wv).
// Block streams: eps (cached seq), b (cached, L3-hot), Z/mu/lv (NT stores).
__global__ __launch_bounds__(256) void k_scan(
        const float* __restrict__ bg,
        const float* __restrict__ eps,
        const float* __restrict__ tilde_psi,
        const float* __restrict__ log_tilde_sigma,
        const float* __restrict__ log_sigma_init,
        float* __restrict__ Zout,
        float* __restrict__ muout,
        float* __restrict__ lvout) {
    const int lane = threadIdx.x & 63;
    const int wv   = threadIdx.x >> 6;
    const int s    = blockIdx.x >> 11;            // / (N/4) = 2048
    const int g    = blockIdx.x & 2047;
    const int n    = g * 4 + wv;

    const float psi    = tilde_psi[0];
    const float lts    = log_tilde_sigma[0];
    const float lsi    = log_sigma_init[0];
    const float sigma  = expf(lts);
    const float sigma0 = expf(lsi);
    const float lvv    = 2.f * lts;

    // all global loads upfront
    const size_t chain = ((size_t)s * N + n) * (T / 4);   // float4 units
    const float4* e4 = (const float4*)eps + chain;
    const float4* b4 = (const float4*)bg + (size_t)n * (T / 4);
    const float4 eA = e4[lane],      eB = e4[64 + lane];
    const float4 bA = b4[lane],      bB = b4[64 + lane];

    const float pj1 = psi, pj2 = psi * psi, pj3 = pj2 * psi, pj4 = pj2 * pj2;
    const float wd0 = pj4, wd1 = wd0 * wd0, wd2 = wd1 * wd1,
                wd3 = wd2 * wd2, wd4 = wd3 * wd3, wd5 = wd4 * wd4;
    // p4l = psi^(4*lane)
    float p4l = 1.f;
    {
        float pw = pj4;
        p4l *= (lane & 1)  ? pw : 1.f; pw *= pw;
        p4l *= (lane & 2)  ? pw : 1.f; pw *= pw;
        p4l *= (lane & 4)  ? pw : 1.f; pw *= pw;
        p4l *= (lane & 8)  ? pw : 1.f; pw *= pw;
        p4l *= (lane & 16) ? pw : 1.f; pw *= pw;
        p4l *= (lane & 32) ? pw : 1.f;
    }

    float4* z4 = (float4*)Zout  + chain;
    float4* m4 = (float4*)muout + chain;
    float4* l4 = (float4*)lvout + chain;

    float Zlast = 0.f;
    #pragma unroll
    for (int seg = 0; seg < 2; ++seg) {
        const float4 e  = seg ? eB : eA;
        const float4 bq = seg ? bB : bA;

        const float sg0 = (seg == 0 && lane == 0) ? sigma0 : sigma;
        // local inclusive scan from zero state
        const float z0 = bq.x + sg0 * e.x;
        const float z1 = psi * z0 + (bq.y + sigma * e.y);
        const float z2 = psi * z1 + (bq.z + sigma * e.z);
        const float z3 = psi * z2 + (bq.w + sigma * e.w);

        // wave-level weighted inclusive scan of carries (psi^4 per step)
        float v = z3, up;
        up = __shfl_up(v, 1);  v += (lane >= 1)  ? wd0 * up : 0.f;
        up = __shfl_up(v, 2);  v += (lane >= 2)  ? wd1 * up : 0.f;
        up = __shfl_up(v, 4);  v += (lane >= 4)  ? wd2 * up : 0.f;
        up = __shfl_up(v, 8);  v += (lane >= 8)  ? wd3 * up : 0.f;
        up = __shfl_up(v, 16); v += (lane >= 16) ? wd4 * up : 0.f;
        up = __shfl_up(v, 32); v += (lane >= 32) ? wd5 * up : 0.f;

        float Zprev = __shfl_up(v, 1);
        Zprev = (lane == 0) ? 0.f : Zprev;
        Zprev += p4l * Zlast;                  // bridge from segment A

        const float Z0 = z0 + pj1 * Zprev;
        const float Z1 = z1 + pj2 * Zprev;
        const float Z2 = z2 + pj3 * Zprev;
        const float Z3 = z3 + pj4 * Zprev;

        nt_store4(&z4[seg * 64 + lane], make_float4(Z0, Z1, Z2, Z3));
        nt_store4(&m4[seg * 64 + lane],
                  make_float4(Z0 - sg0 * e.x, Z1 - sigma * e.y,
                              Z2 - sigma * e.z, Z3 - sigma * e.w));
        nt_store4(&l4[seg * 64 + lane],
                  (seg == 0 && lane == 0)
                      ? make_float4(2.f * lsi, lvv, lvv, lvv)
                      : make_float4(lvv, lvv, lvv, lvv));

        Zlast = __shfl(Z3, 63);                // Z_255 broadcast
    }
}

// fallback lv fill (only if ws too small; then b lives in lvout)
__global__ __launch_bounds__(256) void k_lv(
        float* __restrict__ lv,
        const float* __restrict__ lts,
        const float* __restrict__ lsi) {
    int i = blockIdx.x * blockDim.x + threadIdx.x;    // float4 index
    float v = 2.0f * lts[0];
    float4 o = make_float4(v, v, v, v);
    if ((i & (T / 4 - 1)) == 0) o.x = 2.0f * lsi[0];
    ((float4*)lv)[i] = o;
}

extern "C" void kernel_launch(void* const* d_in, const int* in_sizes, int n_in,
                              void* d_out, int out_size, void* d_ws, size_t ws_size,
                              hipStream_t stream) {
    const float* drivers   = (const float*)d_in[0];
    const float* cov       = (const float*)d_in[1];
    const float* Y         = (const float*)d_in[2];
    const float* eps       = (const float*)d_in[3];
    const float* tilde_psi = (const float*)d_in[4];
    const float* gamma_w   = (const float*)d_in[5];
    const float* alpha_w   = (const float*)d_in[6];
    const float* aY        = (const float*)d_in[7];
    const float* lts       = (const float*)d_in[8];
    const float* mu_init   = (const float*)d_in[9];
    const float* lsi       = (const float*)d_in[10];

    float* out   = (float*)d_out;
    const size_t SNT = (size_t)S * N * T;
    float* Zout  = out;
    float* muout = out + SNT;
    float* lvout = out + 2 * SNT;

    const size_t bbytes = (size_t)N * T * sizeof(float);
    const bool ws_ok = (ws_size >= bbytes);
    float* b = ws_ok ? (float*)d_ws : lvout;      // observed ws_size ~1 GiB

    k_bias<<<N / 4, 256, 0, stream>>>(drivers, cov, Y, gamma_w,
                                      alpha_w, aY, mu_init, b);
    k_scan<<<S * (N / 4), 256, 0, stream>>>(b, eps, tilde_psi, lts, lsi,
                                            Zout, muout, lvout);
    if (!ws_ok) {
        k_lv<<<(SNT / 4) / 256, 256, 0, stream>>>(lvout, lts, lsi);
    }
}

// Round 13
// 138.976 us; speedup vs baseline: 1.2761x; 1.0464x over previous
//
#include <hip/hip_runtime.h>

#define N 8192
#define T 512
#define S 4

typedef float fx4 __attribute__((ext_vector_type(4)));

__device__ __forceinline__ float dot4(float4 a, float4 b) {
    return a.x*b.x + a.y*b.y + a.z*b.z + a.w*b.w;
}
__device__ __forceinline__ void nt_store4(float4* p, float4 v) {
    fx4 r; r.x = v.x; r.y = v.y; r.z = v.z; r.w = v.w;
    __builtin_nontemporal_store(r, (fx4*)p);
}

// ---------------- K1: thread-per-t bias, pure sequential streaming ----------
// b[n*T+t] = proj(n,t) + aY*Y[n,t-1] (t>=1);  b[n*T+0] = mu_init + proj.
// Block owns 2048 contiguous ids; unroll 4 => 24 cached loads in flight.
__global__ __launch_bounds__(256) void k_bias(
        const float* __restrict__ drivers,
        const float* __restrict__ cov,
        const float* __restrict__ Y,
        const float* __restrict__ gamma_w,
        const float* __restrict__ alpha_w,
        const float* __restrict__ alpha_Y_lag,
        const float* __restrict__ mu_init,
        float* __restrict__ b) {
    const float4* g4 = (const float4*)gamma_w;
    const float4* a4 = (const float4*)alpha_w;
    const float4 g0 = g4[0], g1 = g4[1];
    const float4 w0 = a4[0], w1 = a4[1], w2 = a4[2], w3 = a4[3];
    const float aY   = alpha_Y_lag[0];
    const float mu0c = mu_init[0];

    const size_t base = (size_t)blockIdx.x * 2048 + threadIdx.x;
    const float4* d4 = (const float4*)drivers;
    const float4* c4 = (const float4*)cov;

    #pragma unroll 4
    for (int it = 0; it < 8; ++it) {
        const size_t id = base + (size_t)it * 256;       // id = n*T + t
        float4 dA = d4[id * 2], dB = d4[id * 2 + 1];
        float4 cA = c4[id * 4], cB = c4[id * 4 + 1];
        float4 cC = c4[id * 4 + 2], cD = c4[id * 4 + 3];
        const float yprev = Y[id > 0 ? id - 1 : 0];      // coalesced
        const float proj = dot4(dA, g0) + dot4(dB, g1)
                         + dot4(cA, w0) + dot4(cB, w1)
                         + dot4(cC, w2) + dot4(cD, w3);
        const int t = (int)(id & (T - 1));
        b[id] = (t == 0) ? (mu0c + proj) : (proj + aY * yprev);
    }
}

// ---------------- K2: sample-major wave scan, no LDS, no barriers ----------
// blockIdx = s*(N/4) + g ; wave wv handles chain (s, n = 4g+wv).
// Block streams: eps (cached seq), b (cached, L3-hot), Z/mu/lv (NT stores).
__global__ __launch_bounds__(256) void k_scan(
        const float* __restrict__ bg,
        const float* __restrict__ eps,
        const float* __restrict__ tilde_psi,
        const float* __restrict__ log_tilde_sigma,
        const float* __restrict__ log_sigma_init,
        float* __restrict__ Zout,
        float* __restrict__ muout,
        float* __restrict__ lvout) {
    const int lane = threadIdx.x & 63;
    const int wv   = threadIdx.x >> 6;
    const int s    = blockIdx.x >> 11;            // / (N/4) = 2048
    const int g    = blockIdx.x & 2047;
    const int n    = g * 4 + wv;

    const float psi    = tilde_psi[0];
    const float lts    = log_tilde_sigma[0];
    const float lsi    = log_sigma_init[0];
    const float sigma  = expf(lts);
    const float sigma0 = expf(lsi);
    const float lvv    = 2.f * lts;

    // all global loads upfront
    const size_t chain = ((size_t)s * N + n) * (T / 4);   // float4 units
    const float4* e4 = (const float4*)eps + chain;
    const float4* b4 = (const float4*)bg + (size_t)n * (T / 4);
    const float4 eA = e4[lane],      eB = e4[64 + lane];
    const float4 bA = b4[lane],      bB = b4[64 + lane];

    const float pj1 = psi, pj2 = psi * psi, pj3 = pj2 * psi, pj4 = pj2 * pj2;
    const float wd0 = pj4, wd1 = wd0 * wd0, wd2 = wd1 * wd1,
                wd3 = wd2 * wd2, wd4 = wd3 * wd3, wd5 = wd4 * wd4;
    // p4l = psi^(4*lane)
    float p4l = 1.f;
    {
        float pw = pj4;
        p4l *= (lane & 1)  ? pw : 1.f; pw *= pw;
        p4l *= (lane & 2)  ? pw : 1.f; pw *= pw;
        p4l *= (lane & 4)  ? pw : 1.f; pw *= pw;
        p4l *= (lane & 8)  ? pw : 1.f; pw *= pw;
        p4l *= (lane & 16) ? pw : 1.f; pw *= pw;
        p4l *= (lane & 32) ? pw : 1.f;
    }

    float4* z4 = (float4*)Zout  + chain;
    float4* m4 = (float4*)muout + chain;
    float4* l4 = (float4*)lvout + chain;

    float Zlast = 0.f;
    #pragma unroll
    for (int seg = 0; seg < 2; ++seg) {
        const float4 e  = seg ? eB : eA;
        const float4 bq = seg ? bB : bA;

        const float sg0 = (seg == 0 && lane == 0) ? sigma0 : sigma;
        // local inclusive scan from zero state
        const float z0 = bq.x + sg0 * e.x;
        const float z1 = psi * z0 + (bq.y + sigma * e.y);
        const float z2 = psi * z1 + (bq.z + sigma * e.z);
        const float z3 = psi * z2 + (bq.w + sigma * e.w);

        // wave-level weighted inclusive scan of carries (psi^4 per step)
        float v = z3, up;
        up = __shfl_up(v, 1);  v += (lane >= 1)  ? wd0 * up : 0.f;
        up = __shfl_up(v, 2);  v += (lane >= 2)  ? wd1 * up : 0.f;
        up = __shfl_up(v, 4);  v += (lane >= 4)  ? wd2 * up : 0.f;
        up = __shfl_up(v, 8);  v += (lane >= 8)  ? wd3 * up : 0.f;
        up = __shfl_up(v, 16); v += (lane >= 16) ? wd4 * up : 0.f;
        up = __shfl_up(v, 32); v += (lane >= 32) ? wd5 * up : 0.f;

        float Zprev = __shfl_up(v, 1);
        Zprev = (lane == 0) ? 0.f : Zprev;
        Zprev += p4l * Zlast;                  // bridge from segment A

        const float Z0 = z0 + pj1 * Zprev;
        const float Z1 = z1 + pj2 * Zprev;
        const float Z2 = z2 + pj3 * Zprev;
        const float Z3 = z3 + pj4 * Zprev;

        nt_store4(&z4[seg * 64 + lane], make_float4(Z0, Z1, Z2, Z3));
        nt_store4(&m4[seg * 64 + lane],
                  make_float4(Z0 - sg0 * e.x, Z1 - sigma * e.y,
                              Z2 - sigma * e.z, Z3 - sigma * e.w));
        nt_store4(&l4[seg * 64 + lane],
                  (seg == 0 && lane == 0)
                      ? make_float4(2.f * lsi, lvv, lvv, lvv)
                      : make_float4(lvv, lvv, lvv, lvv));

        Zlast = __shfl(Z3, 63);                // Z_255 broadcast
    }
}

// fallback lv fill (only if ws too small; then b lives in lvout)
__global__ __launch_bounds__(256) void k_lv(
        float* __restrict__ lv,
        const float* __restrict__ lts,
        const float* __restrict__ lsi) {
    int i = blockIdx.x * blockDim.x + threadIdx.x;    // float4 index
    float v = 2.0f * lts[0];
    float4 o = make_float4(v, v, v, v);
    if ((i & (T / 4 - 1)) == 0) o.x = 2.0f * lsi[0];
    ((float4*)lv)[i] = o;
}

extern "C" void kernel_launch(void* const* d_in, const int* in_sizes, int n_in,
                              void* d_out, int out_size, void* d_ws, size_t ws_size,
                              hipStream_t stream) {
    const float* drivers   = (const float*)d_in[0];
    const float* cov       = (const float*)d_in[1];
    const float* Y         = (const float*)d_in[2];
    const float* eps       = (const float*)d_in[3];
    const float* tilde_psi = (const float*)d_in[4];
    const float* gamma_w   = (const float*)d_in[5];
    const float* alpha_w   = (const float*)d_in[6];
    const float* aY        = (const float*)d_in[7];
    const float* lts       = (const float*)d_in[8];
    const float* mu_init   = (const float*)d_in[9];
    const float* lsi       = (const float*)d_in[10];

    float* out   = (float*)d_out;
    const size_t SNT = (size_t)S * N * T;
    float* Zout  = out;
    float* muout = out + SNT;
    float* lvout = out + 2 * SNT;

    const size_t bbytes = (size_t)N * T * sizeof(float);
    const bool ws_ok = (ws_size >= bbytes);
    float* b = ws_ok ? (float*)d_ws : lvout;      // observed ws_size ~1 GiB

    k_bias<<<(N * T) / 2048, 256, 0, stream>>>(drivers, cov, Y, gamma_w,
                                               alpha_w, aY, mu_init, b);
    k_scan<<<S * (N / 4), 256, 0, stream>>>(b, eps, tilde_psi, lts, lsi,
                                            Zout, muout, lvout);
    if (!ws_ok) {
        k_lv<<<(SNT / 4) / 256, 256, 0, stream>>>(lvout, lts, lsi);
    }
}